// Round 1
// baseline (129.298 us; speedup 1.0000x reference)
//
#include <hip/hip_runtime.h>

#define WINDOW 20
#define EPS 1e-8f

// Problem shape (fixed by setup_inputs)
constexpr int B = 16;
constexpr int F = 257;
constexpr int T = 8000;

// Pass 1: frame_sum[b,t] = sum_f mag[b,f,t]
__global__ void __launch_bounds__(256) frame_sum_kernel(
    const float* __restrict__ mag, float* __restrict__ fs) {
    int idx = blockIdx.x * blockDim.x + threadIdx.x; // b*T + t
    if (idx >= B * T) return;
    int b = idx / T;
    int t = idx - b * T;
    const float* p = mag + (size_t)b * F * T + t;
    float s = 0.f;
    #pragma unroll 1
    for (int f = 0; f < F; ++f) s += p[(size_t)f * T];
    fs[idx] = s;
}

// Pass 2: mean[b,t] = windowed mean of frame sums / F + bias;
//         norm[b,f,t] = mag[b,f,t] / (mean + eps)
__global__ void __launch_bounds__(256) norm_kernel(
    const float* __restrict__ mag, const float* __restrict__ fs,
    const float* __restrict__ bias, float* __restrict__ out_norm,
    float* __restrict__ out_mean) {
    int idx = blockIdx.x * blockDim.x + threadIdx.x; // b*T + t
    if (idx >= B * T) return;
    int b = idx / T;
    int t = idx - b * T;

    int start = t - (WINDOW - 1);
    if (start < 0) start = 0;
    float ws = 0.f;
    #pragma unroll 1
    for (int s = start; s <= t; ++s) ws += fs[b * T + s];
    float count = (float)((t - start + 1) * F);
    float mean = ws / count + bias[0];
    out_mean[idx] = mean;

    float inv = 1.0f / (mean + EPS);
    const float* p = mag + (size_t)b * F * T + t;
    float* q = out_norm + (size_t)b * F * T + t;
    #pragma unroll 1
    for (int f = 0; f < F; ++f) q[(size_t)f * T] = p[(size_t)f * T] * inv;
}

extern "C" void kernel_launch(void* const* d_in, const int* in_sizes, int n_in,
                              void* d_out, int out_size, void* d_ws, size_t ws_size,
                              hipStream_t stream) {
    const float* mag  = (const float*)d_in[0];
    const float* bias = (const float*)d_in[1];
    float* out_norm = (float*)d_out;                       // B*F*T floats
    float* out_mean = (float*)d_out + (size_t)B * F * T;   // B*T floats
    float* fs = (float*)d_ws;                              // B*T floats scratch

    int n = B * T;
    int blocks = (n + 255) / 256;
    frame_sum_kernel<<<blocks, 256, 0, stream>>>(mag, fs);
    norm_kernel<<<blocks, 256, 0, stream>>>(mag, fs, bias, out_norm, out_mean);
}

// Round 2
// 67.826 us; speedup vs baseline: 1.9063x; 1.9063x over previous
//
#include <hip/hip_runtime.h>

#define WINDOW 20
#define EPS 1e-8f

constexpr int B = 16;
constexpr int F = 257;
constexpr int T = 8000;
constexpr int TQ = T / 4;          // 2000 float4 quads per row
constexpr int NQ = B * F * TQ;     // total float4 quads in mag

// Pass 1: frame_sum[b,t] = sum_f mag[b,f,t]
// Block: 256 threads = 4 f-groups x 64 t-quads (256 t values via float4).
// Grid: (ceil(TQ/64)=32, B)
__global__ void __launch_bounds__(256) frame_sum_kernel(
    const float* __restrict__ mag, float* __restrict__ fs) {
    const int b  = blockIdx.y;
    const int tx = threadIdx.x & 63;        // t-quad within tile
    const int fg = threadIdx.x >> 6;        // f-group 0..3
    const int tq = blockIdx.x * 64 + tx;    // global t-quad

    float4 acc = make_float4(0.f, 0.f, 0.f, 0.f);
    if (tq < TQ) {
        const float4* p = (const float4*)(mag + (size_t)b * F * T) + tq;
        #pragma unroll 4
        for (int f = fg; f < F; f += 4) {
            float4 v = p[(size_t)f * TQ];
            acc.x += v.x; acc.y += v.y; acc.z += v.z; acc.w += v.w;
        }
    }

    __shared__ float4 red[4][64];
    red[fg][tx] = acc;
    __syncthreads();

    if (threadIdx.x < 64) {
        float4 a = red[0][threadIdx.x];
        float4 c = red[1][threadIdx.x];
        float4 d = red[2][threadIdx.x];
        float4 e = red[3][threadIdx.x];
        float4 s;
        s.x = (a.x + c.x) + (d.x + e.x);
        s.y = (a.y + c.y) + (d.y + e.y);
        s.z = (a.z + c.z) + (d.z + e.z);
        s.w = (a.w + c.w) + (d.w + e.w);
        int q = blockIdx.x * 64 + threadIdx.x;
        if (q < TQ) ((float4*)(fs + (size_t)b * T))[q] = s;
    }
}

// Pass 2: mean[b,t] = win_sum/count + bias; inv[b,t] = 1/(mean+eps)
__global__ void __launch_bounds__(256) mean_kernel(
    const float* __restrict__ fs, const float* __restrict__ bias,
    float* __restrict__ out_mean, float* __restrict__ inv) {
    int idx = blockIdx.x * blockDim.x + threadIdx.x; // b*T + t
    if (idx >= B * T) return;
    int b = idx / T;
    int t = idx - b * T;

    int start = t - (WINDOW - 1);
    if (start < 0) start = 0;
    float ws = 0.f;
    const float* p = fs + (size_t)b * T;
    #pragma unroll
    for (int k = 0; k < WINDOW; ++k) {
        int s = start + k;
        if (s <= t) ws += p[s];
    }
    float count = (float)((t - start + 1) * F);
    float mean = ws / count + bias[0];
    out_mean[idx] = mean;
    inv[idx] = 1.0f / (mean + EPS);
}

// Pass 3: norm[b,f,t] = mag[b,f,t] * inv[b,t]  (pure float4 stream)
__global__ void __launch_bounds__(256) norm_kernel(
    const float4* __restrict__ mag4, const float4* __restrict__ inv4,
    float4* __restrict__ out4) {
    int stride = gridDim.x * blockDim.x;
    for (int i = blockIdx.x * blockDim.x + threadIdx.x; i < NQ; i += stride) {
        float4 v = mag4[i];
        unsigned u  = (unsigned)i;
        unsigned tq = u % (unsigned)TQ;
        unsigned bf = u / (unsigned)TQ;
        unsigned b  = bf / (unsigned)F;
        float4 w = inv4[b * TQ + tq];
        v.x *= w.x; v.y *= w.y; v.z *= w.z; v.w *= w.w;
        out4[i] = v;
    }
}

extern "C" void kernel_launch(void* const* d_in, const int* in_sizes, int n_in,
                              void* d_out, int out_size, void* d_ws, size_t ws_size,
                              hipStream_t stream) {
    const float* mag  = (const float*)d_in[0];
    const float* bias = (const float*)d_in[1];
    float* out_norm = (float*)d_out;                       // B*F*T floats
    float* out_mean = (float*)d_out + (size_t)B * F * T;   // B*T floats
    float* fs  = (float*)d_ws;                             // B*T floats
    float* inv = (float*)d_ws + (size_t)B * T;             // B*T floats

    dim3 g1((TQ + 63) / 64, B);
    frame_sum_kernel<<<g1, 256, 0, stream>>>(mag, fs);

    int n = B * T;
    mean_kernel<<<(n + 255) / 256, 256, 0, stream>>>(fs, bias, out_mean, inv);

    norm_kernel<<<2048, 256, 0, stream>>>(
        (const float4*)mag, (const float4*)inv, (float4*)out_norm);
}

// Round 3
// 52.624 us; speedup vs baseline: 2.4570x; 1.2889x over previous
//
#include <hip/hip_runtime.h>

#define WINDOW 20
#define EPS 1e-8f

constexpr int B = 16;
constexpr int F = 257;
constexpr int T = 8000;
constexpr int TQ = T / 4;              // 2000 float4 quads per (b,f) row
constexpr int CHUNK_Q = 32;            // quads per chunk (128 columns)
constexpr int NCH = 4;                 // chunks per block
constexpr int TILE_Q = CHUNK_Q * NCH;  // 128 quads per block tile
constexpr int NTILES = (TQ + TILE_Q - 1) / TILE_Q;  // 16

// One fused pass: read mag once into registers, reduce column sums via LDS,
// compute sliding-window means, normalize from registers, store.
__global__ void __launch_bounds__(512) fused_kernel(
    const float* __restrict__ mag, const float* __restrict__ bias,
    float* __restrict__ out_norm, float* __restrict__ out_mean) {

  const int b    = blockIdx.y;
  const int q0   = blockIdx.x * TILE_Q;
  const int tid  = threadIdx.x;
  const int q    = tid & (CHUNK_Q - 1);  // quad within chunk 0..31
  const int rg   = tid >> 5;             // row group 0..15
  const int wave = tid >> 6;
  const int lane = tid & 63;

  const float4* magq = (const float4*)(mag + (size_t)b * F * T);
  float4* outq = (float4*)(out_norm + (size_t)b * F * T);
  const float bs = bias[0];

  __shared__ float4 red[16][CHUNK_Q];          // [rg][q] partial column sums
  __shared__ float  cs[20 + CHUNK_Q * 4];      // [0..19] halo/tail, [20..147] chunk
  __shared__ float4 inv4[CHUNK_Q];             // 1/(mean+eps) per local column

  // ---- once per block: left-halo column sums (20 columns before tile) ----
  if (wave < 5) {
    int qh = q0 - 5 + wave;
    float4 hs = make_float4(0.f, 0.f, 0.f, 0.f);
    if (qh >= 0) {
      #pragma unroll
      for (int r = 0; r < 4; ++r) {
        float4 tv = magq[(size_t)(lane + (r << 6)) * TQ + qh];
        hs.x += tv.x; hs.y += tv.y; hs.z += tv.z; hs.w += tv.w;
      }
      if (lane == 0) {
        float4 tv = magq[(size_t)256 * TQ + qh];
        hs.x += tv.x; hs.y += tv.y; hs.z += tv.z; hs.w += tv.w;
      }
    }
    #pragma unroll
    for (int off = 32; off > 0; off >>= 1) {
      hs.x += __shfl_down(hs.x, off);
      hs.y += __shfl_down(hs.y, off);
      hs.z += __shfl_down(hs.z, off);
      hs.w += __shfl_down(hs.w, off);
    }
    if (lane == 0) {
      cs[4 * wave + 0] = hs.x;
      cs[4 * wave + 1] = hs.y;
      cs[4 * wave + 2] = hs.z;
      cs[4 * wave + 3] = hs.w;
    }
  }
  // fenced by sync A of chunk 0 before first read

  for (int ch = 0; ch < NCH; ++ch) {
    const int cq0 = q0 + ch * CHUNK_Q;
    if (cq0 >= TQ) break;                     // block-uniform
    const int qc = min(CHUNK_Q, TQ - cq0);
    const bool act = (q < qc);

    // ---- load chunk into registers + per-thread column partials ----
    float4 v[16];
    float4 v16 = make_float4(0.f, 0.f, 0.f, 0.f);
    float4 acc = make_float4(0.f, 0.f, 0.f, 0.f);
    if (act) {
      const float4* p = magq + cq0 + q;
      #pragma unroll
      for (int it = 0; it < 16; ++it) {
        float4 tv = p[(size_t)(rg + (it << 4)) * TQ];
        v[it] = tv;
        acc.x += tv.x; acc.y += tv.y; acc.z += tv.z; acc.w += tv.w;
      }
      if (rg == 0) {                          // fold row f=256 in
        v16 = p[(size_t)256 * TQ];
        acc.x += v16.x; acc.y += v16.y; acc.z += v16.z; acc.w += v16.w;
      }
    }
    red[rg][q] = acc;
    __syncthreads();                          // A

    // ---- finalize column sums (32 threads) ----
    if (tid < CHUNK_Q) {
      float4 s = make_float4(0.f, 0.f, 0.f, 0.f);
      #pragma unroll
      for (int r = 0; r < 16; ++r) {
        float4 a = red[r][tid];
        s.x += a.x; s.y += a.y; s.z += a.z; s.w += a.w;
      }
      cs[20 + 4 * tid + 0] = s.x;
      cs[20 + 4 * tid + 1] = s.y;
      cs[20 + 4 * tid + 2] = s.z;
      cs[20 + 4 * tid + 3] = s.w;
    }
    __syncthreads();                          // B

    // ---- window means + inverse (128 threads) ----
    const int ncols = qc * 4;
    if (tid < ncols) {
      int t = cq0 * 4 + tid;
      float ws = 0.f;
      #pragma unroll
      for (int k = 0; k < WINDOW; ++k) ws += cs[20 + tid - k];
      int nwin = (t < WINDOW - 1) ? (t + 1) : WINDOW;
      float mean = ws / (float)(nwin * F) + bs;
      out_mean[b * T + t] = mean;
      ((float*)inv4)[tid] = 1.0f / (mean + EPS);
    }
    __syncthreads();                          // C

    // ---- normalize from registers + store; slide tail into halo ----
    if (act) {
      float4 w = inv4[q];
      float4* o = outq + cq0 + q;
      #pragma unroll
      for (int it = 0; it < 16; ++it) {
        float4 tv = v[it];
        tv.x *= w.x; tv.y *= w.y; tv.z *= w.z; tv.w *= w.w;
        o[(size_t)(rg + (it << 4)) * TQ] = tv;
      }
      if (rg == 0) {
        float4 tv = v16;
        tv.x *= w.x; tv.y *= w.y; tv.z *= w.z; tv.w *= w.w;
        o[(size_t)256 * TQ] = tv;
      }
    }
    if (tid < 20) cs[tid] = cs[ncols + tid];  // tail -> halo (fenced by next A)
  }
}

extern "C" void kernel_launch(void* const* d_in, const int* in_sizes, int n_in,
                              void* d_out, int out_size, void* d_ws, size_t ws_size,
                              hipStream_t stream) {
  const float* mag  = (const float*)d_in[0];
  const float* bias = (const float*)d_in[1];
  float* out_norm = (float*)d_out;                      // B*F*T floats
  float* out_mean = (float*)d_out + (size_t)B * F * T;  // B*T floats

  dim3 grid(NTILES, B);
  fused_kernel<<<grid, 512, 0, stream>>>(mag, bias, out_norm, out_mean);
}